// Round 5
// baseline (1393.837 us; speedup 1.0000x reference)
//
#include <hip/hip_runtime.h>
#include <hip/hip_bf16.h>
#include <math.h>

#define BS 32
#define QN 256
#define TN 128
#define NCLS 2048
#define NTGT (BS * TN)  // 4096

// ---------------------------------------------------------------------------
// Detect whether agent_mask is stored as 1-byte bools or 4-byte int32.
// ---------------------------------------------------------------------------
__global__ void detect_mask_layout(const unsigned char* __restrict__ m, int* flag) {
    __shared__ int found;
    if (threadIdx.x == 0) found = 0;
    __syncthreads();
    int local = 0;
    for (int i = threadIdx.x; i < BS * QN; i += blockDim.x) {
        if ((i & 3) != 0 && m[i] != 0) local = 1;
    }
    if (local) atomicOr(&found, 1);
    __syncthreads();
    if (threadIdx.x == 0) *flag = found;  // 1 = byte layout, 0 = int32 layout
}

// ---------------------------------------------------------------------------
// C[b,q,jj] = -(softmax(logits[b,q,:])[labels_flat[jj]]), zeroed if masked.
// ---------------------------------------------------------------------------
__global__ __launch_bounds__(256) void compute_C_kernel(
    const float* __restrict__ logits, const int* __restrict__ labels,
    const unsigned char* __restrict__ mask_b, const int* __restrict__ use_bg,
    const int* __restrict__ layout_flag, float* __restrict__ C) {
    __shared__ float prob_sh[NCLS];
    __shared__ int lab_sh[NTGT];
    __shared__ float red[4];

    const int tid = threadIdx.x;
    const int bq = blockIdx.x;  // b*QN + q
    const float* row = logits + (size_t)bq * NCLS;

    for (int k = tid; k < NTGT; k += 256) lab_sh[k] = labels[k];

    float x[8];
    float m = -INFINITY;
#pragma unroll
    for (int k = 0; k < 8; k++) {
        x[k] = row[tid + k * 256];
        m = fmaxf(m, x[k]);
    }
#pragma unroll
    for (int off = 32; off >= 1; off >>= 1) m = fmaxf(m, __shfl_xor(m, off));
    if ((tid & 63) == 0) red[tid >> 6] = m;
    __syncthreads();
    m = fmaxf(fmaxf(red[0], red[1]), fmaxf(red[2], red[3]));
    __syncthreads();

    float e[8];
    float s = 0.f;
#pragma unroll
    for (int k = 0; k < 8; k++) {
        e[k] = expf(x[k] - m);
        s += e[k];
    }
#pragma unroll
    for (int off = 32; off >= 1; off >>= 1) s += __shfl_xor(s, off);
    if ((tid & 63) == 0) red[tid >> 6] = s;
    __syncthreads();
    s = ((red[0] + red[1]) + red[2]) + red[3];

#pragma unroll
    for (int k = 0; k < 8; k++) prob_sh[tid + k * 256] = e[k] / s;

    const int ub = *use_bg;
    int am;
    if (*layout_flag)
        am = mask_b[bq];
    else
        am = ((const int*)mask_b)[bq];
    const bool zero_row = (ub == 0) && (am == 0);
    __syncthreads();

    float* Crow = C + (size_t)bq * NTGT;
#pragma unroll
    for (int k = 0; k < 16; k++) {
        const int jj = tid + k * 256;
        Crow[jj] = zero_row ? 0.0f : -prob_sh[lab_sh[jj]];
    }
}

// ---------------------------------------------------------------------------
// Transpose block-diagonal part of C into CT[b][i][q].
// ---------------------------------------------------------------------------
__global__ __launch_bounds__(256) void transpose_kernel(const float* __restrict__ C,
                                                        float* __restrict__ CT) {
    __shared__ float tile[TN][65];
    const int b = blockIdx.x;
    const int q0 = blockIdx.y * 64;
    const int tid = threadIdx.x;

    const float* src = C + (size_t)(b * QN + q0) * NTGT + b * TN;
#pragma unroll
    for (int it = 0; it < 32; it++) {
        const int idx = tid + it * 256;
        const int ql = idx >> 7;
        const int i = idx & 127;
        tile[i][ql] = src[(size_t)ql * NTGT + i];
    }
    __syncthreads();
    float* dst = CT + (size_t)b * TN * QN + q0;
#pragma unroll
    for (int it = 0; it < 32; it++) {
        const int idx = tid + it * 256;
        const int i = idx >> 6;
        const int ql = idx & 63;
        dst[(size_t)i * QN + ql] = tile[i][ql];
    }
}

// ---------------------------------------------------------------------------
// Cross-lane helpers.
// ---------------------------------------------------------------------------
template <int CTRL>
__device__ __forceinline__ double dpp_mov_f64(double x) {
    union { double d; int i[2]; } a, r;
    a.d = x;
    r.i[0] = __builtin_amdgcn_update_dpp(0, a.i[0], CTRL, 0xF, 0xF, true);
    r.i[1] = __builtin_amdgcn_update_dpp(0, a.i[1], CTRL, 0xF, 0xF, true);
    return r.d;
}
__device__ __forceinline__ double read_lane_f64(double x, int srclane) {
    union { double d; int i[2]; } a, r;
    a.d = x;
    r.i[0] = __builtin_amdgcn_readlane(a.i[0], srclane);
    r.i[1] = __builtin_amdgcn_readlane(a.i[1], srclane);
    return r.d;
}
// broadcast u[i] from register mirrors (lane i>>1 holds rows 2l, 2l+1)
__device__ __forceinline__ double read_u_reg(double u0, double u1, int i) {
    union { double d; int i2[2]; } a0, a1, r;
    a0.d = u0;
    a1.d = u1;
    const int ow = i >> 1;
    const int lo0 = __builtin_amdgcn_readlane(a0.i2[0], ow);
    const int hi0 = __builtin_amdgcn_readlane(a0.i2[1], ow);
    const int lo1 = __builtin_amdgcn_readlane(a1.i2[0], ow);
    const int hi1 = __builtin_amdgcn_readlane(a1.i2[1], ow);
    r.i2[0] = (i & 1) ? lo1 : lo0;
    r.i2[1] = (i & 1) ? hi1 : hi0;
    return r.d;
}

#define QUAD_XOR1 0xB1   // quad_perm(1,0,3,2)
#define QUAD_XOR2 0x4E   // quad_perm(2,3,0,1)
#define ROW_ROR4  0x124  // row_ror:4
#define ROW_ROR8  0x128  // row_ror:8

// first tied column index from 4 slot-ballots (scalar, wave-uniform)
__device__ __forceinline__ int first_tied(unsigned long long B0, unsigned long long B1,
                                          unsigned long long B2, unsigned long long B3) {
    int jmin = 0x7fffffff;
    if (B0) { const int c = ((__ffsll((long long)B0) - 1) << 2) + 0; jmin = c < jmin ? c : jmin; }
    if (B1) { const int c = ((__ffsll((long long)B1) - 1) << 2) + 1; jmin = c < jmin ? c : jmin; }
    if (B2) { const int c = ((__ffsll((long long)B2) - 1) << 2) + 2; jmin = c < jmin ? c : jmin; }
    if (B3) { const int c = ((__ffsll((long long)B3) - 1) << 2) + 3; jmin = c < jmin ? c : jmin; }
    return jmin;
}

// ---------------------------------------------------------------------------
// Jonker-Volgenant, exact replica of reference _lsa() on the transposed
// problem (nr=TN=128 rows=targets, nc=QN=256 cols=queries). One wave/batch.
// Lane owns cols 4l..4l+3 (d, v, SC, path, row4col in regs) and rows 2l,2l+1
// (u, du, SR, col4row in regs). The ONLY LDS op in the round loop is the
// cost-row ds_read_b128 — and it is issued SPECULATIVELY one pop ahead:
// on the tie fast path the next selection (first bit of the tied-set
// ballot) is independent of the current row's d-update, so its row load
// overlaps the current pop's ALU. Commit check: the selection stands unless
// some improvement lands at or below the current min (then full DPP-tree
// reduce, bit-exact vs scipy's fresh argmin).
// ---------------------------------------------------------------------------
__global__ __launch_bounds__(64) void lsa_kernel(const float* __restrict__ C,
                                                 const float* __restrict__ CT,
                                                 float* __restrict__ rows_out,
                                                 float* __restrict__ cols_out) {
    const int b = blockIdx.x;
    const int lane = threadIdx.x;  // 0..63
    const int j0 = lane * 4;

    __shared__ float cost_sh[TN * QN];  // [i][q], 128 KB
    __shared__ int col4row_sh[TN];      // epilogue only

    if (CT) {
        const float4* src = (const float4*)(CT + (size_t)b * TN * QN);
        float4* dst = (float4*)cost_sh;
#pragma unroll 8
        for (int it = 0; it < TN * QN / 4 / 64; it++) {
            const int idx = it * 64 + lane;
            dst[idx] = src[idx];
        }
    } else {
        const float* cbsrc = C + (size_t)b * QN * NTGT + b * TN;
        for (int it = 0; it < 512; it++) {
            const int j = it >> 1;
            const int i = lane + 64 * (it & 1);
            cost_sh[i * QN + j] = cbsrc[(size_t)j * NTGT + i];
        }
    }
    __syncthreads();

    // persistent per-lane state
    double v0 = 0.0, v1 = 0.0, v2 = 0.0, v3 = 0.0;  // col duals
    double u0 = 0.0, u1 = 0.0;                      // row duals
    int rc0 = -1, rc1 = -1, rc2 = -1, rc3 = -1;     // row4col (owned cols)
    int cr0 = -1, cr1 = -1;                         // col4row (owned rows)

    for (int cur = 0; cur < TN; cur++) {
        double dv0 = INFINITY, dv1 = INFINITY, dv2 = INFINITY, dv3 = INFINITY;
        double dm0 = INFINITY, dm1 = INFINITY, dm2 = INFINITY, dm3 = INFINITY;
        double duA = 0.0, duB = 0.0;
        int sc = 0, sr = 0;
        int p0 = 0, p1 = 0, p2 = 0, p3 = 0;
        if (lane == (cur >> 1)) sr = 1 << (cur & 1);  // SR[cur]

        int i = cur;
        double m_d = 0.0;
        unsigned long long B0 = 0, B1 = 0, B2 = 0, B3 = 0;
        int sink = 0;

        // prologue: load row cur + u[cur]
        float4 cc = *(const float4*)(cost_sh + i * QN + j0);
        double ui = read_u_reg(u0, u1, i);

        while (true) {
            // ---- speculative select + next-row prefetch (independent of cc) ----
            const unsigned long long Ball = B0 | B1 | B2 | B3;
            int jspec = 0, sowner = 0, sslot = 0, krcspec = -1;
            int ispec = 0;
            if (Ball) {
                jspec = first_tied(B0, B1, B2, B3);
                sowner = jspec >> 2;
                sslot = jspec & 3;
                const int rsel = (sslot == 0) ? rc0 : (sslot == 1) ? rc1 : (sslot == 2) ? rc2 : rc3;
                krcspec = __builtin_amdgcn_readlane(rsel, sowner);
                ispec = krcspec >= 0 ? krcspec : 0;
            }
            const float4 ccs = *(const float4*)(cost_sh + ispec * QN + j0);
            const double uis = read_u_reg(u0, u1, ispec);

            // ---- consume current row (numpy order, strict r < d) ----
            const double ca0 = ((m_d + (double)cc.x) - ui) - v0;
            const double ca1 = ((m_d + (double)cc.y) - ui) - v1;
            const double ca2 = ((m_d + (double)cc.z) - ui) - v2;
            const double ca3 = ((m_d + (double)cc.w) - ui) - v3;
            const bool i0 = !(sc & 1) && (ca0 < dv0);
            const bool i1 = !(sc & 2) && (ca1 < dv1);
            const bool i2 = !(sc & 4) && (ca2 < dv2);
            const bool i3 = !(sc & 8) && (ca3 < dv3);
            const unsigned long long chk =
                __ballot(i0 && (ca0 <= m_d)) | __ballot(i1 && (ca1 <= m_d)) |
                __ballot(i2 && (ca2 <= m_d)) | __ballot(i3 && (ca3 <= m_d));
            if (i0) { dv0 = ca0; dm0 = ca0; p0 = i; }
            if (i1) { dv1 = ca1; dm1 = ca1; p1 = i; }
            if (i2) { dv2 = ca2; dm2 = ca2; p2 = i; }
            if (i3) { dv3 = ca3; dm3 = ca3; p3 = i; }

            if (chk == 0ull && Ball) {
                // ---- fast commit of speculative pop ----
                const unsigned long long bit = 1ull << sowner;
                if (sslot == 0) B0 &= ~bit;
                else if (sslot == 1) B1 &= ~bit;
                else if (sslot == 2) B2 &= ~bit;
                else B3 &= ~bit;
                if (krcspec < 0) { sink = jspec; break; }
                if (lane == sowner) {
                    sc |= 1 << sslot;
                    if (sslot == 0) dm0 = INFINITY;
                    else if (sslot == 1) dm1 = INFINITY;
                    else if (sslot == 2) dm2 = INFINITY;
                    else dm3 = INFINITY;
                }
                if (lane == (krcspec >> 1)) {
                    if (krcspec & 1) { duB = m_d; sr |= 2; }
                    else { duA = m_d; sr |= 1; }
                }
                i = krcspec;
                cc = ccs;   // pipeline register: load already in flight/done
                ui = uis;
                continue;
            }

            // ---- slow path: full argmin (f64 DPP min tree + eq-ballots) ----
            double lm = fmin(fmin(dm0, dm1), fmin(dm2, dm3));
            lm = fmin(lm, dpp_mov_f64<QUAD_XOR1>(lm));
            lm = fmin(lm, dpp_mov_f64<QUAD_XOR2>(lm));
            lm = fmin(lm, dpp_mov_f64<ROW_ROR4>(lm));
            lm = fmin(lm, dpp_mov_f64<ROW_ROR8>(lm));
            const double r0 = read_lane_f64(lm, 0);
            const double r1 = read_lane_f64(lm, 16);
            const double r2 = read_lane_f64(lm, 32);
            const double r3 = read_lane_f64(lm, 48);
            m_d = fmin(fmin(r0, r1), fmin(r2, r3));
            B0 = __ballot(dm0 == m_d);
            B1 = __ballot(dm1 == m_d);
            B2 = __ballot(dm2 == m_d);
            B3 = __ballot(dm3 == m_d);

            const int jmin = first_tied(B0, B1, B2, B3);
            const int owner = jmin >> 2;
            const int slot = jmin & 3;
            const unsigned long long bit = 1ull << owner;
            if (slot == 0) B0 &= ~bit;
            else if (slot == 1) B1 &= ~bit;
            else if (slot == 2) B2 &= ~bit;
            else B3 &= ~bit;
            const int rsel2 = (slot == 0) ? rc0 : (slot == 1) ? rc1 : (slot == 2) ? rc2 : rc3;
            const int krc = __builtin_amdgcn_readlane(rsel2, owner);
            if (krc < 0) { sink = jmin; break; }
            if (lane == owner) {
                sc |= 1 << slot;
                if (slot == 0) dm0 = INFINITY;
                else if (slot == 1) dm1 = INFINITY;
                else if (slot == 2) dm2 = INFINITY;
                else dm3 = INFINITY;
            }
            if (lane == (krc >> 1)) {
                if (krc & 1) { duB = m_d; sr |= 2; }
                else { duA = m_d; sr |= 1; }
            }
            i = krc;
            cc = *(const float4*)(cost_sh + i * QN + j0);
            ui = read_u_reg(u0, u1, i);
        }

        // ---- round end: dual updates (scipy _lsap_body), all registers ----
        if (sc & 1) v0 -= m_d - dv0;
        if (sc & 2) v1 -= m_d - dv1;
        if (sc & 4) v2 -= m_d - dv2;
        if (sc & 8) v3 -= m_d - dv3;
        if (sr & 1) u0 += (2 * lane == cur) ? m_d : (m_d - duA);
        if (sr & 2) u1 += (2 * lane + 1 == cur) ? m_d : (m_d - duB);

        // ---- augment: all-lane uniform replay via readlanes (no LDS) ----
        int j = sink;
        while (true) {
            const int aslot = j & 3;
            const int aowner = j >> 2;
            const int psel = (aslot == 0) ? p0 : (aslot == 1) ? p1 : (aslot == 2) ? p2 : p3;
            const int pi = __builtin_amdgcn_readlane(psel, aowner);
            if (lane == aowner) {
                if (aslot == 0) rc0 = pi;
                else if (aslot == 1) rc1 = pi;
                else if (aslot == 2) rc2 = pi;
                else rc3 = pi;
            }
            const int cowner = pi >> 1;
            const int cslot = pi & 1;
            const int csel = cslot ? cr1 : cr0;
            const int nj = __builtin_amdgcn_readlane(csel, cowner);
            if (lane == cowner) {
                if (cslot) cr1 = j;
                else cr0 = j;
            }
            j = nj;
            if (pi == cur) break;
        }
    }

    // ---- epilogue: rank by col4row value (values distinct) ----
    col4row_sh[2 * lane] = cr0;
    col4row_sh[2 * lane + 1] = cr1;
    __syncthreads();
#pragma unroll
    for (int t = 0; t < 2; t++) {
        const int ii = 2 * lane + t;
        const int myv = t ? cr1 : cr0;
        int rank = 0;
        for (int t2 = 0; t2 < TN; t2++) rank += (col4row_sh[t2] < myv) ? 1 : 0;
        rows_out[b * TN + rank] = (float)myv;
        cols_out[b * TN + rank] = (float)ii;
    }
}

extern "C" void kernel_launch(void* const* d_in, const int* in_sizes, int n_in,
                              void* d_out, int out_size, void* d_ws, size_t ws_size,
                              hipStream_t stream) {
    const float* logits = (const float*)d_in[0];                  // [32,256,2048] f32
    const int* labels = (const int*)d_in[1];                      // [32,128] i32
    const unsigned char* mask_b = (const unsigned char*)d_in[2];  // [32,256] bool/i32
    const int* use_bg = (const int*)d_in[3];                      // scalar

    float* C = (float*)d_out;  // 32*256*4096
    float* rows_out = C + (size_t)BS * QN * NTGT;
    float* cols_out = rows_out + BS * TN;

    int* flag = (int*)d_ws;
    const size_t ct_off = 4096;
    const size_t ct_bytes = (size_t)BS * TN * QN * sizeof(float);  // 4 MB
    const bool useCT = ws_size >= ct_off + ct_bytes;
    float* CT = useCT ? (float*)((char*)d_ws + ct_off) : nullptr;

    detect_mask_layout<<<1, 256, 0, stream>>>(mask_b, flag);
    compute_C_kernel<<<BS * QN, 256, 0, stream>>>(logits, labels, mask_b, use_bg, flag, C);
    if (useCT) {
        dim3 tg(BS, QN / 64);
        transpose_kernel<<<tg, 256, 0, stream>>>(C, CT);
    }
    lsa_kernel<<<BS, 64, 0, stream>>>(C, CT, rows_out, cols_out);
}

// Round 6
// 1255.642 us; speedup vs baseline: 1.1101x; 1.1101x over previous
//
#include <hip/hip_runtime.h>
#include <hip/hip_bf16.h>
#include <math.h>

#define BS 32
#define QN 256
#define TN 128
#define NCLS 2048
#define NTGT (BS * TN)  // 4096

// ---------------------------------------------------------------------------
// Detect whether agent_mask is stored as 1-byte bools or 4-byte int32.
// ---------------------------------------------------------------------------
__global__ void detect_mask_layout(const unsigned char* __restrict__ m, int* flag) {
    __shared__ int found;
    if (threadIdx.x == 0) found = 0;
    __syncthreads();
    int local = 0;
    for (int i = threadIdx.x; i < BS * QN; i += blockDim.x) {
        if ((i & 3) != 0 && m[i] != 0) local = 1;
    }
    if (local) atomicOr(&found, 1);
    __syncthreads();
    if (threadIdx.x == 0) *flag = found;  // 1 = byte layout, 0 = int32 layout
}

// ---------------------------------------------------------------------------
// C[b,q,jj] = -(softmax(logits[b,q,:])[labels_flat[jj]]), zeroed if masked.
// ---------------------------------------------------------------------------
__global__ __launch_bounds__(256) void compute_C_kernel(
    const float* __restrict__ logits, const int* __restrict__ labels,
    const unsigned char* __restrict__ mask_b, const int* __restrict__ use_bg,
    const int* __restrict__ layout_flag, float* __restrict__ C) {
    __shared__ float prob_sh[NCLS];
    __shared__ int lab_sh[NTGT];
    __shared__ float red[4];

    const int tid = threadIdx.x;
    const int bq = blockIdx.x;  // b*QN + q
    const float* row = logits + (size_t)bq * NCLS;

    for (int k = tid; k < NTGT; k += 256) lab_sh[k] = labels[k];

    float x[8];
    float m = -INFINITY;
#pragma unroll
    for (int k = 0; k < 8; k++) {
        x[k] = row[tid + k * 256];
        m = fmaxf(m, x[k]);
    }
#pragma unroll
    for (int off = 32; off >= 1; off >>= 1) m = fmaxf(m, __shfl_xor(m, off));
    if ((tid & 63) == 0) red[tid >> 6] = m;
    __syncthreads();
    m = fmaxf(fmaxf(red[0], red[1]), fmaxf(red[2], red[3]));
    __syncthreads();

    float e[8];
    float s = 0.f;
#pragma unroll
    for (int k = 0; k < 8; k++) {
        e[k] = expf(x[k] - m);
        s += e[k];
    }
#pragma unroll
    for (int off = 32; off >= 1; off >>= 1) s += __shfl_xor(s, off);
    if ((tid & 63) == 0) red[tid >> 6] = s;
    __syncthreads();
    s = ((red[0] + red[1]) + red[2]) + red[3];

#pragma unroll
    for (int k = 0; k < 8; k++) prob_sh[tid + k * 256] = e[k] / s;

    const int ub = *use_bg;
    int am;
    if (*layout_flag)
        am = mask_b[bq];
    else
        am = ((const int*)mask_b)[bq];
    const bool zero_row = (ub == 0) && (am == 0);
    __syncthreads();

    float* Crow = C + (size_t)bq * NTGT;
#pragma unroll
    for (int k = 0; k < 16; k++) {
        const int jj = tid + k * 256;
        Crow[jj] = zero_row ? 0.0f : -prob_sh[lab_sh[jj]];
    }
}

// ---------------------------------------------------------------------------
// Transpose block-diagonal part of C into CT[b][i][q].
// ---------------------------------------------------------------------------
__global__ __launch_bounds__(256) void transpose_kernel(const float* __restrict__ C,
                                                        float* __restrict__ CT) {
    __shared__ float tile[TN][65];
    const int b = blockIdx.x;
    const int q0 = blockIdx.y * 64;
    const int tid = threadIdx.x;

    const float* src = C + (size_t)(b * QN + q0) * NTGT + b * TN;
#pragma unroll
    for (int it = 0; it < 32; it++) {
        const int idx = tid + it * 256;
        const int ql = idx >> 7;
        const int i = idx & 127;
        tile[i][ql] = src[(size_t)ql * NTGT + i];
    }
    __syncthreads();
    float* dst = CT + (size_t)b * TN * QN + q0;
#pragma unroll
    for (int it = 0; it < 32; it++) {
        const int idx = tid + it * 256;
        const int i = idx >> 6;
        const int ql = idx & 63;
        dst[(size_t)i * QN + ql] = tile[i][ql];
    }
}

// ---------------------------------------------------------------------------
// Cross-lane helpers.
// ---------------------------------------------------------------------------
template <int CTRL>
__device__ __forceinline__ double dpp_mov_f64(double x) {
    union { double d; int i[2]; } a, r;
    a.d = x;
    r.i[0] = __builtin_amdgcn_update_dpp(0, a.i[0], CTRL, 0xF, 0xF, true);
    r.i[1] = __builtin_amdgcn_update_dpp(0, a.i[1], CTRL, 0xF, 0xF, true);
    return r.d;
}
__device__ __forceinline__ double read_lane_f64(double x, int srclane) {
    union { double d; int i[2]; } a, r;
    a.d = x;
    r.i[0] = __builtin_amdgcn_readlane(a.i[0], srclane);
    r.i[1] = __builtin_amdgcn_readlane(a.i[1], srclane);
    return r.d;
}

#define QUAD_XOR1 0xB1   // quad_perm(1,0,3,2)
#define QUAD_XOR2 0x4E   // quad_perm(2,3,0,1)
#define ROW_ROR4  0x124  // row_ror:4
#define ROW_ROR8  0x128  // row_ror:8

// first tied column index from 4 slot-ballots (scalar, wave-uniform)
__device__ __forceinline__ int first_tied(unsigned long long B0, unsigned long long B1,
                                          unsigned long long B2, unsigned long long B3) {
    int jmin = 0x7fffffff;
    if (B0) { const int c = ((__ffsll((long long)B0) - 1) << 2) + 0; jmin = c < jmin ? c : jmin; }
    if (B1) { const int c = ((__ffsll((long long)B1) - 1) << 2) + 1; jmin = c < jmin ? c : jmin; }
    if (B2) { const int c = ((__ffsll((long long)B2) - 1) << 2) + 2; jmin = c < jmin ? c : jmin; }
    if (B3) { const int c = ((__ffsll((long long)B3) - 1) << 2) + 3; jmin = c < jmin ? c : jmin; }
    return jmin;
}

// ---------------------------------------------------------------------------
// Jonker-Volgenant, exact replica of reference _lsa() on the transposed
// problem (nr=TN=128 rows=targets, nc=QN=256 cols=queries). One wave/batch.
// Lane owns cols 4l..4l+3 (d, v, SC, path, row4col in regs) and rows 2l,2l+1
// (u mirror, du, SR, col4row in regs); u also write-through to LDS for
// broadcast reads. Round loop LDS ops: cost-row ds_read_b128 + u ds_read_b64,
// both issued ONE POP AHEAD: the next pop is guessed at the tail of the
// current commit (first bit of the tied-set ballot) — valid unless some
// improvement from the just-consumed row lands at or below the current min
// (then full DPP-tree reduce; bit-exact vs scipy's fresh argmin).
// ---------------------------------------------------------------------------
__global__ __launch_bounds__(64) void lsa_kernel(const float* __restrict__ C,
                                                 const float* __restrict__ CT,
                                                 float* __restrict__ rows_out,
                                                 float* __restrict__ cols_out) {
    const int b = blockIdx.x;
    const int lane = threadIdx.x;  // 0..63
    const int j0 = lane * 4;

    __shared__ float cost_sh[TN * QN];  // [i][q], 128 KB
    __shared__ double u_sh[TN];
    __shared__ int col4row_sh[TN];      // epilogue only

    if (CT) {
        const float4* src = (const float4*)(CT + (size_t)b * TN * QN);
        float4* dst = (float4*)cost_sh;
#pragma unroll 8
        for (int it = 0; it < TN * QN / 4 / 64; it++) {
            const int idx = it * 64 + lane;
            dst[idx] = src[idx];
        }
    } else {
        const float* cbsrc = C + (size_t)b * QN * NTGT + b * TN;
        for (int it = 0; it < 512; it++) {
            const int j = it >> 1;
            const int i = lane + 64 * (it & 1);
            cost_sh[i * QN + j] = cbsrc[(size_t)j * NTGT + i];
        }
    }
    u_sh[2 * lane] = 0.0;
    u_sh[2 * lane + 1] = 0.0;
    __syncthreads();

    // persistent per-lane state
    double v0 = 0.0, v1 = 0.0, v2 = 0.0, v3 = 0.0;  // col duals (owned cols)
    double u0 = 0.0, u1 = 0.0;                      // row duals (owned rows)
    int rc0 = -1, rc1 = -1, rc2 = -1, rc3 = -1;     // row4col (owned cols)
    int cr0 = -1, cr1 = -1;                         // col4row (owned rows)

    for (int cur = 0; cur < TN; cur++) {
        double dv0 = INFINITY, dv1 = INFINITY, dv2 = INFINITY, dv3 = INFINITY;
        double duA = 0.0, duB = 0.0;
        int sc = 0, sr = 0;
        int p0 = 0, p1 = 0, p2 = 0, p3 = 0;
        if (lane == (cur >> 1)) sr = 1 << (cur & 1);  // SR[cur]

        int i = cur;
        double m_d = 0.0;
        unsigned long long B0 = 0, B1 = 0, B2 = 0, B3 = 0;
        int sink = 0;
        bool have_g = false;
        int jg = 0, krcg = 0;

        // prologue: issue loads for row cur
        float4 cc = *(const float4*)(cost_sh + i * QN + j0);
        double ui = u_sh[i];
        float4 gcc = cc;   // init only
        double gui = ui;

        while (true) {
            // ---- consume current row (numpy order, strict r < d) ----
            const double ca0 = ((m_d + (double)cc.x) - ui) - v0;
            const double ca1 = ((m_d + (double)cc.y) - ui) - v1;
            const double ca2 = ((m_d + (double)cc.z) - ui) - v2;
            const double ca3 = ((m_d + (double)cc.w) - ui) - v3;
            const bool i0 = !(sc & 1) && (ca0 < dv0);
            const bool i1 = !(sc & 2) && (ca1 < dv1);
            const bool i2 = !(sc & 4) && (ca2 < dv2);
            const bool i3 = !(sc & 8) && (ca3 < dv3);
            const unsigned long long chk =
                __ballot(i0 && (ca0 <= m_d)) | __ballot(i1 && (ca1 <= m_d)) |
                __ballot(i2 && (ca2 <= m_d)) | __ballot(i3 && (ca3 <= m_d));
            if (i0) { dv0 = ca0; p0 = i; }
            if (i1) { dv1 = ca1; p1 = i; }
            if (i2) { dv2 = ca2; p2 = i; }
            if (i3) { dv3 = ca3; p3 = i; }

            if (chk == 0ull && have_g) {
                // ---- fast commit of guessed pop (m_d, tied set unchanged) ----
                if (krcg < 0) { sink = jg; break; }
                const int gowner = jg >> 2;
                const int gslot = jg & 3;
                if (lane == gowner) sc |= 1 << gslot;
                if (lane == (krcg >> 1)) {
                    if (krcg & 1) { duB = m_d; sr |= 2; }
                    else { duA = m_d; sr |= 1; }
                }
                i = krcg;
                cc = gcc;   // data arrived one iteration ago
                ui = gui;
            } else {
                // ---- slow path: full argmin over sc-masked dv ----
                const double md0 = (sc & 1) ? INFINITY : dv0;
                const double md1 = (sc & 2) ? INFINITY : dv1;
                const double md2 = (sc & 4) ? INFINITY : dv2;
                const double md3 = (sc & 8) ? INFINITY : dv3;
                double lm = fmin(fmin(md0, md1), fmin(md2, md3));
                lm = fmin(lm, dpp_mov_f64<QUAD_XOR1>(lm));
                lm = fmin(lm, dpp_mov_f64<QUAD_XOR2>(lm));
                lm = fmin(lm, dpp_mov_f64<ROW_ROR4>(lm));
                lm = fmin(lm, dpp_mov_f64<ROW_ROR8>(lm));
                const double r0 = read_lane_f64(lm, 0);
                const double r1 = read_lane_f64(lm, 16);
                const double r2 = read_lane_f64(lm, 32);
                const double r3 = read_lane_f64(lm, 48);
                m_d = fmin(fmin(r0, r1), fmin(r2, r3));
                B0 = __ballot(!(sc & 1) && (dv0 == m_d));
                B1 = __ballot(!(sc & 2) && (dv1 == m_d));
                B2 = __ballot(!(sc & 4) && (dv2 == m_d));
                B3 = __ballot(!(sc & 8) && (dv3 == m_d));

                const int jmin = first_tied(B0, B1, B2, B3);
                const int owner = jmin >> 2;
                const int slot = jmin & 3;
                const unsigned long long bit = 1ull << owner;
                if (slot == 0) B0 &= ~bit;
                else if (slot == 1) B1 &= ~bit;
                else if (slot == 2) B2 &= ~bit;
                else B3 &= ~bit;
                const int rsel = (slot == 0) ? rc0 : (slot == 1) ? rc1 : (slot == 2) ? rc2 : rc3;
                const int krc = __builtin_amdgcn_readlane(rsel, owner);
                if (krc < 0) { sink = jmin; break; }
                if (lane == owner) sc |= 1 << slot;
                if (lane == (krc >> 1)) {
                    if (krc & 1) { duB = m_d; sr |= 2; }
                    else { duA = m_d; sr |= 1; }
                }
                i = krc;
                cc = *(const float4*)(cost_sh + i * QN + j0);
                ui = u_sh[i];
            }

            // ---- guess the pop after this scan; issue its loads now ----
            if ((B0 | B1 | B2 | B3) != 0ull) {
                jg = first_tied(B0, B1, B2, B3);
                const int go = jg >> 2;
                const int gs = jg & 3;
                const unsigned long long gbit = 1ull << go;
                if (gs == 0) B0 &= ~gbit;
                else if (gs == 1) B1 &= ~gbit;
                else if (gs == 2) B2 &= ~gbit;
                else B3 &= ~gbit;
                const int grsel = (gs == 0) ? rc0 : (gs == 1) ? rc1 : (gs == 2) ? rc2 : rc3;
                krcg = __builtin_amdgcn_readlane(grsel, go);
                const int rg = (krcg >= 0) ? krcg : 0;
                gcc = *(const float4*)(cost_sh + rg * QN + j0);
                gui = u_sh[rg];
                have_g = true;
            } else {
                have_g = false;
            }
        }

        // ---- round end: dual updates (scipy _lsap_body), all registers ----
        if (sc & 1) v0 -= m_d - dv0;
        if (sc & 2) v1 -= m_d - dv1;
        if (sc & 4) v2 -= m_d - dv2;
        if (sc & 8) v3 -= m_d - dv3;
        if (sr & 1) u0 += (2 * lane == cur) ? m_d : (m_d - duA);
        if (sr & 2) u1 += (2 * lane + 1 == cur) ? m_d : (m_d - duB);
        u_sh[2 * lane] = u0;        // write-through for broadcast reads
        u_sh[2 * lane + 1] = u1;

        // ---- augment: all-lane uniform replay via readlanes (no LDS) ----
        int j = sink;
        while (true) {
            const int aslot = j & 3;
            const int aowner = j >> 2;
            const int psel = (aslot == 0) ? p0 : (aslot == 1) ? p1 : (aslot == 2) ? p2 : p3;
            const int pi = __builtin_amdgcn_readlane(psel, aowner);
            if (lane == aowner) {
                if (aslot == 0) rc0 = pi;
                else if (aslot == 1) rc1 = pi;
                else if (aslot == 2) rc2 = pi;
                else rc3 = pi;
            }
            const int cowner = pi >> 1;
            const int cslot = pi & 1;
            const int csel = cslot ? cr1 : cr0;
            const int nj = __builtin_amdgcn_readlane(csel, cowner);
            if (lane == cowner) {
                if (cslot) cr1 = j;
                else cr0 = j;
            }
            j = nj;
            if (pi == cur) break;
        }
    }

    // ---- epilogue: rank by col4row value (values distinct) ----
    col4row_sh[2 * lane] = cr0;
    col4row_sh[2 * lane + 1] = cr1;
    __syncthreads();
#pragma unroll
    for (int t = 0; t < 2; t++) {
        const int ii = 2 * lane + t;
        const int myv = t ? cr1 : cr0;
        int rank = 0;
        for (int t2 = 0; t2 < TN; t2++) rank += (col4row_sh[t2] < myv) ? 1 : 0;
        rows_out[b * TN + rank] = (float)myv;
        cols_out[b * TN + rank] = (float)ii;
    }
}

extern "C" void kernel_launch(void* const* d_in, const int* in_sizes, int n_in,
                              void* d_out, int out_size, void* d_ws, size_t ws_size,
                              hipStream_t stream) {
    const float* logits = (const float*)d_in[0];                  // [32,256,2048] f32
    const int* labels = (const int*)d_in[1];                      // [32,128] i32
    const unsigned char* mask_b = (const unsigned char*)d_in[2];  // [32,256] bool/i32
    const int* use_bg = (const int*)d_in[3];                      // scalar

    float* C = (float*)d_out;  // 32*256*4096
    float* rows_out = C + (size_t)BS * QN * NTGT;
    float* cols_out = rows_out + BS * TN;

    int* flag = (int*)d_ws;
    const size_t ct_off = 4096;
    const size_t ct_bytes = (size_t)BS * TN * QN * sizeof(float);  // 4 MB
    const bool useCT = ws_size >= ct_off + ct_bytes;
    float* CT = useCT ? (float*)((char*)d_ws + ct_off) : nullptr;

    detect_mask_layout<<<1, 256, 0, stream>>>(mask_b, flag);
    compute_C_kernel<<<BS * QN, 256, 0, stream>>>(logits, labels, mask_b, use_bg, flag, C);
    if (useCT) {
        dim3 tg(BS, QN / 64);
        transpose_kernel<<<tg, 256, 0, stream>>>(C, CT);
    }
    lsa_kernel<<<BS, 64, 0, stream>>>(C, CT, rows_out, cols_out);
}